// Round 9
// baseline (688.236 us; speedup 1.0000x reference)
//
#include <hip/hip_runtime.h>

// LSTM predictor: B=1024, T=1024, H=51, input=1. Sequential recurrence.
//
// Round 9: single wave per batch element, all 4 gates in-wave, f16-packed
// weights (104 VGPRs resident -- the only layout rounds 1-5 proved can be
// VALU-readable), COMPENSATED double-f16 h:
//   hi = f16(h), lo = f16(h - hi)  ->  hi+lo carries ~22 mantissa bits,
//   recurrence is numerically equivalent to fp32. Round 8's plain-f16 h
//   landed at absmax 2^-8 (threshold 0.95*2^-8): the f16 h error is AT the
//   pass boundary; all fp32-h rounds scored 2^-10. Each gate dot doubles:
//   26 dot2(hi) + 26 dot2(lo); weights register count unchanged.
// h exchange stays register-only: cvt -> DPP row_shl:1 (lane i reads lane
// i+1; verified round 8: wrong direction gave 6x larger error) -> pack ->
// readlane -> SGPR feeds v_dot2 src0. No barriers. fc staged in stride-65
// LDS, reduced every 64 steps. x double-buffered.

#define HID 51
#define SEQ_T 1024
#define NPAIR 26

typedef _Float16 f16;
typedef unsigned int u32;
typedef __attribute__((ext_vector_type(2))) _Float16 half2_t;

static __device__ __forceinline__ float lane_bcast(float v, int lane) {
    return __int_as_float(__builtin_amdgcn_readlane(__float_as_int(v), lane));
}
static __device__ __forceinline__ float fast_sigmoid(float x) {
    float e = __builtin_amdgcn_exp2f(x * -1.44269504088896340736f);
    return __builtin_amdgcn_rcpf(1.0f + e);
}
static __device__ __forceinline__ float fast_tanh(float x) {
    float e = __builtin_amdgcn_exp2f(x * 2.88539008177792681472f);
    return 1.0f - 2.0f * __builtin_amdgcn_rcpf(e + 1.0f);
}

__global__ __launch_bounds__(64)
__attribute__((amdgpu_waves_per_eu(1, 1)))
void lstm_solo_kernel(
    const float* __restrict__ x,      // [B, T]
    const float* __restrict__ W_ih,   // [4H, 1]
    const float* __restrict__ W_hh,   // [4H, H]
    const float* __restrict__ b_ih,   // [4H]
    const float* __restrict__ b_hh,   // [4H]
    const float* __restrict__ fc_w,   // [1, H]
    const float* __restrict__ fc_b,   // [1]
    float* __restrict__ out)          // [B, T]
{
    const int b = blockIdx.x;
    const int l = threadIdx.x;
    const bool act = (l < HID);

    __shared__ float pbuf[64][65];  // fc staging; stride 65 conflict-free

    // ---- pack all 4 gate-rows of W_hh into f16 pairs (104 VGPRs) ----
    u32 w0[NPAIR], w1[NPAIR], w2[NPAIR], w3[NPAIR];
#pragma unroll
    for (int p = 0; p < NPAIR; ++p) {
        float v00=0.f,v01=0.f,v10=0.f,v11=0.f,v20=0.f,v21=0.f,v30=0.f,v31=0.f;
        if (act) {
            const int k0 = 2 * p, k1 = 2 * p + 1;
            v00 = W_hh[(0 * HID + l) * HID + k0];
            v10 = W_hh[(1 * HID + l) * HID + k0];
            v20 = W_hh[(2 * HID + l) * HID + k0];
            v30 = W_hh[(3 * HID + l) * HID + k0];
            if (k1 < HID) {
                v01 = W_hh[(0 * HID + l) * HID + k1];
                v11 = W_hh[(1 * HID + l) * HID + k1];
                v21 = W_hh[(2 * HID + l) * HID + k1];
                v31 = W_hh[(3 * HID + l) * HID + k1];
            }
        }
        half2_t p0 = {(f16)v00, (f16)v01}, p1 = {(f16)v10, (f16)v11};
        half2_t p2 = {(f16)v20, (f16)v21}, p3 = {(f16)v30, (f16)v31};
        w0[p] = __builtin_bit_cast(u32, p0);
        w1[p] = __builtin_bit_cast(u32, p1);
        w2[p] = __builtin_bit_cast(u32, p2);
        w3[p] = __builtin_bit_cast(u32, p3);
        asm volatile("" : "+v"(w0[p]), "+v"(w1[p]), "+v"(w2[p]), "+v"(w3[p]));
    }
    float b0=0.f,b1=0.f,b2=0.f,b3=0.f, wx0=0.f,wx1=0.f,wx2=0.f,wx3=0.f, fcw=0.f;
    if (act) {
        b0 = b_ih[0 * HID + l] + b_hh[0 * HID + l];
        b1 = b_ih[1 * HID + l] + b_hh[1 * HID + l];
        b2 = b_ih[2 * HID + l] + b_hh[2 * HID + l];
        b3 = b_ih[3 * HID + l] + b_hh[3 * HID + l];
        wx0 = W_ih[0 * HID + l];
        wx1 = W_ih[1 * HID + l];
        wx2 = W_ih[2 * HID + l];
        wx3 = W_ih[3 * HID + l];
        fcw = fc_w[l];
    }
    const float fcb = fc_b[0];

    float h = 0.f, c = 0.f;
    float xv = x[b * SEQ_T + l];  // first 64-step chunk of input

#pragma unroll 1
    for (int t0 = 0; t0 < SEQ_T; t0 += 64) {
        // prefetch next chunk now; latency hides under 64 steps of compute
        const int tn = (t0 + 64 < SEQ_T) ? (t0 + 64) : t0;  // clamped re-read
        const float xnext = x[b * SEQ_T + tn + l];

#pragma unroll 1
        for (int i = 0; i < 64; ++i) {
            // ---- split h = hi + lo (double-f16), broadcast via DPP ----
            const f16 hi_h = (f16)h;
            const float hi_f = (float)hi_h;
            const f16 lo_h = (f16)(h - hi_f);
            u32 own_hi = (u32)__builtin_bit_cast(unsigned short, hi_h);
            u32 own_lo = (u32)__builtin_bit_cast(unsigned short, lo_h);
            // row_shl:1 (0x101): lane n gets lane n+1 (within 16-lane row).
            // Even lanes 2p pair with 2p+1; never straddles a row boundary.
            u32 nb_hi = (u32)__builtin_amdgcn_update_dpp(
                0, (int)own_hi, 0x101, 0xf, 0xf, true);
            u32 nb_lo = (u32)__builtin_amdgcn_update_dpp(
                0, (int)own_lo, 0x101, 0xf, 0xf, true);
            const u32 hp2 = own_hi | (nb_hi << 16);  // (hi[2p], hi[2p+1])
            const u32 lp2 = own_lo | (nb_lo << 16);  // (lo[2p], lo[2p+1])

            const float xt = lane_bcast(xv, i);
            float s0 = fmaf(xt, wx0, b0);
            float s1 = fmaf(xt, wx1, b1);
            float s2 = fmaf(xt, wx2, b2);
            float s3 = fmaf(xt, wx3, b3);
#pragma unroll
            for (int p = 0; p < NPAIR; ++p) {
                const int hs = __builtin_amdgcn_readlane((int)hp2, 2 * p);
                const int ls = __builtin_amdgcn_readlane((int)lp2, 2 * p);
                // VOP3P: src0 = SGPR h-pair, src1 = VGPR weight pair
                asm("v_dot2_f32_f16 %0, %2, %1, %0"
                    : "+v"(s0) : "v"(w0[p]), "s"(hs));
                asm("v_dot2_f32_f16 %0, %2, %1, %0"
                    : "+v"(s1) : "v"(w1[p]), "s"(hs));
                asm("v_dot2_f32_f16 %0, %2, %1, %0"
                    : "+v"(s2) : "v"(w2[p]), "s"(hs));
                asm("v_dot2_f32_f16 %0, %2, %1, %0"
                    : "+v"(s3) : "v"(w3[p]), "s"(hs));
                asm("v_dot2_f32_f16 %0, %2, %1, %0"
                    : "+v"(s0) : "v"(w0[p]), "s"(ls));
                asm("v_dot2_f32_f16 %0, %2, %1, %0"
                    : "+v"(s1) : "v"(w1[p]), "s"(ls));
                asm("v_dot2_f32_f16 %0, %2, %1, %0"
                    : "+v"(s2) : "v"(w2[p]), "s"(ls));
                asm("v_dot2_f32_f16 %0, %2, %1, %0"
                    : "+v"(s3) : "v"(w3[p]), "s"(ls));
            }
            const float ig = fast_sigmoid(s0);
            const float fg = fast_sigmoid(s1);
            const float gg = fast_tanh(s2);
            const float og = fast_sigmoid(s3);
            c = fmaf(fg, c, ig * gg);
            h = og * fast_tanh(c);
            // lanes >= 51: zero weights/bias -> h stays 0; contributes 0.
            pbuf[l][i] = h * fcw;  // fc staging, off critical path
        }

        // fc reduce + store (single wave: no barrier; compiler waits lgkm)
        float s2r = 0.f;
#pragma unroll
        for (int k = 0; k < HID; ++k) s2r += pbuf[k][l];
        out[b * SEQ_T + t0 + l] = s2r + fcb;  // coalesced 64-chunk

        xv = xnext;
    }
}

extern "C" void kernel_launch(void* const* d_in, const int* in_sizes, int n_in,
                              void* d_out, int out_size, void* d_ws, size_t ws_size,
                              hipStream_t stream) {
    (void)in_sizes; (void)n_in; (void)d_ws; (void)ws_size; (void)out_size;
    const float* x    = (const float*)d_in[0];
    const float* W_ih = (const float*)d_in[1];
    const float* W_hh = (const float*)d_in[2];
    const float* b_ih = (const float*)d_in[3];
    const float* b_hh = (const float*)d_in[4];
    const float* fc_w = (const float*)d_in[5];
    const float* fc_b = (const float*)d_in[6];
    float* out = (float*)d_out;

    lstm_solo_kernel<<<dim3(1024), dim3(64), 0, stream>>>(
        x, W_ih, W_hh, b_ih, b_hh, fc_w, fc_b, out);
}